// Round 1
// baseline (845.824 us; speedup 1.0000x reference)
//
#include <hip/hip_runtime.h>
#include <hip/hip_bf16.h>
#include <type_traits>

// Problem constants
#define BATCH  16
#define SEQ    1024
#define HIDDEN 1024
#define NHEAD  4
#define DHEAD  256
#define QKVN   2304   // (2*NHEAD+1)*DHEAD

typedef _Float16 f16x8 __attribute__((ext_vector_type(8)));
typedef float    f32x4 __attribute__((ext_vector_type(4)));

// ---------------------------------------------------------------------------
// Transpose fp32 [R][C] -> f16 [C][R]
// ---------------------------------------------------------------------------
__global__ __launch_bounds__(256) void transpose_to_f16(
    const float* __restrict__ in, _Float16* __restrict__ out, int R, int C) {
  __shared__ float tile[64][65];
  int bc = blockIdx.x * 64;   // col base in input
  int br = blockIdx.y * 64;   // row base in input
  int t = threadIdx.x;
  int tr = t >> 6, tc = t & 63;
  for (int i = 0; i < 64; i += 4) {
    int r = br + tr + i;
    tile[tr + i][tc] = in[(size_t)r * C + bc + tc];
  }
  __syncthreads();
  for (int i = 0; i < 64; i += 4) {
    int c = bc + tr + i;
    out[(size_t)c * R + br + tc] = (_Float16)tile[tc][tr + i];
  }
}

// ---------------------------------------------------------------------------
// Transpose v slice of qkv (f16) into vT[b][d][s]
// ---------------------------------------------------------------------------
__global__ __launch_bounds__(256) void transpose_v(
    const _Float16* __restrict__ qkv, _Float16* __restrict__ vT) {
  __shared__ _Float16 tile[64][65];
  int b = blockIdx.z;
  int s0 = blockIdx.x * 64, d0 = blockIdx.y * 64;
  int t = threadIdx.x;
  int tr = t >> 6, tc = t & 63;
  for (int i = 0; i < 64; i += 4) {
    int s = s0 + tr + i;
    tile[tr + i][tc] = qkv[((size_t)(b * SEQ + s)) * QKVN + 2 * NHEAD * DHEAD + d0 + tc];
  }
  __syncthreads();
  for (int i = 0; i < 64; i += 4) {
    int d = d0 + tr + i;
    vT[((size_t)(b * DHEAD + d)) * SEQ + s0 + tc] = tile[tc][tr + i];
  }
}

// ---------------------------------------------------------------------------
// GEMM (B^T form): C[m][n] = sum_k A[m][k] * B[n][k]
// A: fp32 or f16 (converted during staging), B: f16 (N x K), C: fp32 or f16.
// 128x128 tile, BK=32, 4 waves each computing 64x64 via 4x4 MFMA 16x16x32.
// ---------------------------------------------------------------------------
template <typename AT, typename OT>
__global__ __launch_bounds__(256) void gemm_bt(
    const AT* __restrict__ A, const _Float16* __restrict__ B,
    OT* __restrict__ C, int M, int N, int K) {
  __shared__ __align__(16) _Float16 As[128][32];
  __shared__ __align__(16) _Float16 Bs[128][32];
  int bm = blockIdx.x * 128, bn = blockIdx.y * 128;
  int t = threadIdx.x;
  int w = t >> 6, L = t & 63, lane15 = L & 15, quad = L >> 4;
  int wr = (w >> 1) * 64, wc = (w & 1) * 64;
  int srow = t >> 1, scol = (t & 1) * 16;  // each thread stages 16 contiguous elems
  f32x4 acc[4][4] = {};
  for (int k0 = 0; k0 < K; k0 += 32) {
    __syncthreads();
    if constexpr (std::is_same_v<AT, float>) {
      const float4* ap = (const float4*)&A[(size_t)(bm + srow) * K + k0 + scol];
      float4 f0 = ap[0], f1 = ap[1], f2 = ap[2], f3 = ap[3];
      _Float16* dst = &As[srow][scol];
      dst[0]  = (_Float16)f0.x; dst[1]  = (_Float16)f0.y; dst[2]  = (_Float16)f0.z; dst[3]  = (_Float16)f0.w;
      dst[4]  = (_Float16)f1.x; dst[5]  = (_Float16)f1.y; dst[6]  = (_Float16)f1.z; dst[7]  = (_Float16)f1.w;
      dst[8]  = (_Float16)f2.x; dst[9]  = (_Float16)f2.y; dst[10] = (_Float16)f2.z; dst[11] = (_Float16)f2.w;
      dst[12] = (_Float16)f3.x; dst[13] = (_Float16)f3.y; dst[14] = (_Float16)f3.z; dst[15] = (_Float16)f3.w;
    } else {
      const uint4* ap = (const uint4*)&A[(size_t)(bm + srow) * K + k0 + scol];
      *(uint4*)&As[srow][scol]     = ap[0];
      *(uint4*)&As[srow][scol + 8] = ap[1];
    }
    {
      const uint4* bp = (const uint4*)&B[(size_t)(bn + srow) * K + k0 + scol];
      *(uint4*)&Bs[srow][scol]     = bp[0];
      *(uint4*)&Bs[srow][scol + 8] = bp[1];
    }
    __syncthreads();
    f16x8 af[4], bf[4];
    for (int i = 0; i < 4; i++) af[i] = *(f16x8*)&As[wr + i * 16 + lane15][quad * 8];
    for (int j = 0; j < 4; j++) bf[j] = *(f16x8*)&Bs[wc + j * 16 + lane15][quad * 8];
    for (int i = 0; i < 4; i++)
      for (int j = 0; j < 4; j++)
        acc[i][j] = __builtin_amdgcn_mfma_f32_16x16x32_f16(af[i], bf[j], acc[i][j], 0, 0, 0);
  }
  for (int i = 0; i < 4; i++)
    for (int j = 0; j < 4; j++) {
      int gr = bm + wr + i * 16 + quad * 4;
      int gc = bn + wc + j * 16 + lane15;
      for (int r = 0; r < 4; r++) {
        float v = acc[i][j][r];
        if constexpr (std::is_same_v<OT, float>)
          C[(size_t)(gr + r) * N + gc] = v;
        else
          C[(size_t)(gr + r) * N + gc] = (_Float16)v;
      }
    }
}

// ---------------------------------------------------------------------------
// Attention scores + exact softmax, writes attn_prob (fp32) incl. causal zeros.
// Grid: (t_tile=SEQ/64, NHEAD, BATCH). Two passes: pass0 computes row max+sum
// (online), pass1 recomputes S and writes P = exp(s-m)/l. Upper tiles zeroed.
// ---------------------------------------------------------------------------
__global__ __launch_bounds__(256) void attn_kernel(
    const _Float16* __restrict__ qkv, float* __restrict__ P) {
  int ti = blockIdx.x, n = blockIdx.y, b = blockIdx.z;
  __shared__ __align__(16) _Float16 Qs[8][64][32];  // [kchunk][row][k within]
  __shared__ __align__(16) _Float16 Ks[8][64][32];
  int t = threadIdx.x;
  int w = t >> 6, L = t & 63, lane15 = L & 15, quad = L >> 4;
  // Stage Q tile (64 rows x 256 cols f16) in chunk layout
  for (int c = t; c < 2048; c += 256) {
    int row = c >> 5, col8 = c & 31;
    uint4 val = *(const uint4*)&qkv[((size_t)(b * SEQ + ti * 64 + row)) * QKVN + n * DHEAD + col8 * 8];
    *(uint4*)&Qs[col8 >> 2][row][(col8 & 3) * 8] = val;
  }
  float m[4], l[4];
  for (int r = 0; r < 4; r++) { m[r] = -INFINITY; l[r] = 0.f; }
  size_t Pbase = ((size_t)(b * NHEAD + n)) * SEQ * SEQ;
  int trow_base = ti * 64 + w * 16 + quad * 4;
  const float scale = 0.0625f;  // DHEAD^-0.5
  for (int pass = 0; pass < 2; pass++) {
    float rl[4];
    if (pass == 1)
      for (int r = 0; r < 4; r++) rl[r] = 1.0f / l[r];
    for (int si = 0; si <= ti; si++) {
      __syncthreads();  // protect Ks from previous tile's readers
      for (int c = t; c < 2048; c += 256) {
        int row = c >> 5, col8 = c & 31;
        uint4 val = *(const uint4*)&qkv[((size_t)(b * SEQ + si * 64 + row)) * QKVN + NHEAD * DHEAD + n * DHEAD + col8 * 8];
        *(uint4*)&Ks[col8 >> 2][row][(col8 & 3) * 8] = val;
      }
      __syncthreads();
      f32x4 s[4] = {};
      for (int kc = 0; kc < 8; kc++) {
        f16x8 aq = *(f16x8*)&Qs[kc][w * 16 + lane15][quad * 8];
        for (int j = 0; j < 4; j++) {
          f16x8 bk = *(f16x8*)&Ks[kc][j * 16 + lane15][quad * 8];
          s[j] = __builtin_amdgcn_mfma_f32_16x16x32_f16(aq, bk, s[j], 0, 0, 0);
        }
      }
      // scale + causal mask (only bites on diagonal tile si==ti)
      for (int j = 0; j < 4; j++) {
        int col = si * 64 + j * 16 + lane15;
        for (int r = 0; r < 4; r++) {
          float v = s[j][r] * scale;
          if (col > trow_base + r) v = -1e9f;
          s[j][r] = v;
        }
      }
      if (pass == 0) {
        for (int r = 0; r < 4; r++) {
          float mt = fmaxf(fmaxf(s[0][r], s[1][r]), fmaxf(s[2][r], s[3][r]));
          for (int off = 1; off < 16; off <<= 1) mt = fmaxf(mt, __shfl_xor(mt, off, 64));
          float mn = fmaxf(m[r], mt);
          float sum = 0.f;
          for (int j = 0; j < 4; j++) sum += __expf(s[j][r] - mn);
          for (int off = 1; off < 16; off <<= 1) sum += __shfl_xor(sum, off, 64);
          l[r] = l[r] * __expf(m[r] - mn) + sum;
          m[r] = mn;
        }
      } else {
        for (int j = 0; j < 4; j++) {
          int col = si * 64 + j * 16 + lane15;
          for (int r = 0; r < 4; r++) {
            float p = (col > trow_base + r) ? 0.f : __expf(s[j][r] - m[r]) * rl[r];
            P[Pbase + (size_t)(trow_base + r) * SEQ + col] = p;
          }
        }
      }
    }
  }
  // zero-fill fully-masked tiles (cols (ti+1)*64 .. SEQ-1)
  int zc = (15 - ti) * 64;
  if (zc > 0) {
    int zn4 = zc >> 2;
    for (int idx = t; idx < 64 * zn4; idx += 256) {
      int row = idx / zn4, c4 = idx % zn4;
      *(float4*)&P[Pbase + (size_t)(ti * 64 + row) * SEQ + (ti + 1) * 64 + c4 * 4] =
          make_float4(0.f, 0.f, 0.f, 0.f);
    }
  }
}

// ---------------------------------------------------------------------------
// m_attn[b][t][d] = sum_s (mean_n P[b][n][t][s]) * v[b][s][d]   (f16 out)
// Grid: (SEQ/64, BATCH). Causal: only s-tiles <= t-tile contribute.
// ---------------------------------------------------------------------------
__global__ __launch_bounds__(256) void pv_mean_kernel(
    const float* __restrict__ P, const _Float16* __restrict__ vT,
    _Float16* __restrict__ mattn) {
  int ti = blockIdx.x, b = blockIdx.y;
  __shared__ __align__(16) _Float16 Pm[2][64][32];   // mean-P tile, chunk layout
  __shared__ __align__(16) _Float16 Vs[2][256][32];  // vT tile [d][s-chunk]
  int t = threadIdx.x;
  int w = t >> 6, L = t & 63, lane15 = L & 15, quad = L >> 4;
  f32x4 acc[16] = {};
  for (int si = 0; si <= ti; si++) {
    __syncthreads();
    // average P over 4 heads -> f16
    for (int idx = t; idx < 1024; idx += 256) {
      int row = idx >> 4, c4 = idx & 15;
      float4 sum = make_float4(0.f, 0.f, 0.f, 0.f);
      for (int n = 0; n < 4; n++) {
        float4 pv = *(const float4*)&P[(((size_t)(b * NHEAD + n)) * SEQ + ti * 64 + row) * SEQ + si * 64 + c4 * 4];
        sum.x += pv.x; sum.y += pv.y; sum.z += pv.z; sum.w += pv.w;
      }
      _Float16* dst = &Pm[c4 >> 3][row][(c4 * 4) & 31];
      dst[0] = (_Float16)(sum.x * 0.25f); dst[1] = (_Float16)(sum.y * 0.25f);
      dst[2] = (_Float16)(sum.z * 0.25f); dst[3] = (_Float16)(sum.w * 0.25f);
    }
    // stage vT tile: 256 d-rows x 64 s-cols
    for (int idx = t; idx < 2048; idx += 256) {
      int d = idx >> 3, s8 = idx & 7;
      uint4 val = *(const uint4*)&vT[((size_t)(b * DHEAD + d)) * SEQ + si * 64 + s8 * 8];
      *(uint4*)&Vs[s8 >> 2][d][(s8 & 3) * 8] = val;
    }
    __syncthreads();
    for (int kc = 0; kc < 2; kc++) {
      f16x8 ap = *(f16x8*)&Pm[kc][w * 16 + lane15][quad * 8];
      for (int j = 0; j < 16; j++) {
        f16x8 bv = *(f16x8*)&Vs[kc][j * 16 + lane15][quad * 8];
        acc[j] = __builtin_amdgcn_mfma_f32_16x16x32_f16(ap, bv, acc[j], 0, 0, 0);
      }
    }
  }
  for (int j = 0; j < 16; j++) {
    int row = b * SEQ + ti * 64 + w * 16 + quad * 4;
    int col = j * 16 + lane15;
    for (int r = 0; r < 4; r++)
      mattn[(size_t)(row + r) * DHEAD + col] = (_Float16)acc[j][r];
  }
}

// ---------------------------------------------------------------------------
// Workspace layout (f16 elems): wqkvT[2304*1024] | woutT[1024*256] |
// qkvb[16384*2304] | vT[16*256*1024] | mattn[16384*256]  => ~97.5 MB total
// ---------------------------------------------------------------------------
extern "C" void kernel_launch(void* const* d_in, const int* in_sizes, int n_in,
                              void* d_out, int out_size, void* d_ws, size_t ws_size,
                              hipStream_t stream) {
  const float* x     = (const float*)d_in[0];
  const float* w_qkv = (const float*)d_in[1];
  const float* w_out = (const float*)d_in[2];
  float* out = (float*)d_out;
  float* P   = out + (size_t)BATCH * SEQ * HIDDEN;  // attn_prob region

  _Float16* wqkvT = (_Float16*)d_ws;                       // [2304][1024]
  _Float16* woutT = wqkvT + (size_t)QKVN * HIDDEN;         // [1024][256]
  _Float16* qkvb  = woutT + (size_t)HIDDEN * DHEAD;        // [16384][2304]
  _Float16* vT    = qkvb + (size_t)BATCH * SEQ * QKVN;     // [16][256][1024]
  _Float16* mattn = vT + (size_t)BATCH * DHEAD * SEQ;      // [16384][256]

  // weights: transpose + cast to f16
  transpose_to_f16<<<dim3(QKVN / 64, HIDDEN / 64), 256, 0, stream>>>(w_qkv, wqkvT, HIDDEN, QKVN);
  transpose_to_f16<<<dim3(HIDDEN / 64, DHEAD / 64), 256, 0, stream>>>(w_out, woutT, DHEAD, HIDDEN);
  // qkv = x @ w_qkv  (f16 out)
  gemm_bt<float, _Float16><<<dim3(BATCH * SEQ / 128, QKVN / 128), 256, 0, stream>>>(
      x, wqkvT, qkvb, BATCH * SEQ, QKVN, HIDDEN);
  // v transpose for PV GEMM
  transpose_v<<<dim3(SEQ / 64, DHEAD / 64, BATCH), 256, 0, stream>>>(qkvb, vT);
  // scores + softmax -> P (fp32 output region)
  attn_kernel<<<dim3(SEQ / 64, NHEAD, BATCH), 256, 0, stream>>>(qkvb, P);
  // m_attn = mean_n(P) @ v
  pv_mean_kernel<<<dim3(SEQ / 64, BATCH), 256, 0, stream>>>(P, vT, mattn);
  // out = m_attn @ w_out
  gemm_bt<_Float16, float><<<dim3(BATCH * SEQ / 128, HIDDEN / 128), 256, 0, stream>>>(
      mattn, woutT, out, BATCH * SEQ, HIDDEN, DHEAD);
}

// Round 2
// 763.513 us; speedup vs baseline: 1.1078x; 1.1078x over previous
//
#include <hip/hip_runtime.h>
#include <hip/hip_bf16.h>
#include <type_traits>

#define BATCH  16
#define SEQ    1024
#define HIDDEN 1024
#define NHEAD  4
#define DHEAD  256
#define QKVN   2304   // (2*NHEAD+1)*DHEAD

typedef _Float16 f16x8 __attribute__((ext_vector_type(8)));
typedef float    f32x4 __attribute__((ext_vector_type(4)));

__device__ __forceinline__ void gll16(const void* g, void* l) {
  __builtin_amdgcn_global_load_lds(
      (const __attribute__((address_space(1))) unsigned int*)g,
      (__attribute__((address_space(3))) unsigned int*)l, 16, 0, 0);
}

// ---------------------------------------------------------------------------
// fp32 -> f16 elementwise (x pre-conversion)
// ---------------------------------------------------------------------------
__global__ __launch_bounds__(256) void f32_to_f16(
    const float* __restrict__ in, _Float16* __restrict__ out) {
  int i4 = blockIdx.x * 256 + threadIdx.x;
  float4 v = ((const float4*)in)[i4];
  _Float16 h4[4] = {(_Float16)v.x, (_Float16)v.y, (_Float16)v.z, (_Float16)v.w};
  *(uint2*)&out[(size_t)i4 * 4] = *(uint2*)h4;
}

// ---------------------------------------------------------------------------
// Transpose fp32 [R][C] -> f16 [C][R]
// ---------------------------------------------------------------------------
__global__ __launch_bounds__(256) void transpose_to_f16(
    const float* __restrict__ in, _Float16* __restrict__ out, int R, int C) {
  __shared__ float tile[64][65];
  int bc = blockIdx.x * 64, br = blockIdx.y * 64;
  int t = threadIdx.x;
  int tr = t >> 6, tc = t & 63;
  for (int i = 0; i < 64; i += 4)
    tile[tr + i][tc] = in[(size_t)(br + tr + i) * C + bc + tc];
  __syncthreads();
  for (int i = 0; i < 64; i += 4)
    out[(size_t)(bc + tr + i) * R + br + tc] = (_Float16)tile[tc][tr + i];
}

// ---------------------------------------------------------------------------
// Transpose v slice of qkv (f16) into vT[b][d][s]
// ---------------------------------------------------------------------------
__global__ __launch_bounds__(256) void transpose_v(
    const _Float16* __restrict__ qkv, _Float16* __restrict__ vT) {
  __shared__ _Float16 tile[64][65];
  int b = blockIdx.z;
  int s0 = blockIdx.x * 64, d0 = blockIdx.y * 64;
  int t = threadIdx.x;
  int tr = t >> 6, tc = t & 63;
  for (int i = 0; i < 64; i += 4)
    tile[tr + i][tc] = qkv[((size_t)(b * SEQ + s0 + tr + i)) * QKVN + 2 * NHEAD * DHEAD + d0 + tc];
  __syncthreads();
  for (int i = 0; i < 64; i += 4)
    vT[((size_t)(b * DHEAD + d0 + tr + i)) * SEQ + s0 + tc] = tile[tc][tr + i];
}

// ---------------------------------------------------------------------------
// GEMM (B^T): C[m][n] = sum_k A[m][k]*B[n][k]; A,B f16; 128x128 tile BK=32.
// m97-style global_load_lds staging (16B/lane, lane-linear LDS layout).
// ---------------------------------------------------------------------------
template <typename OT>
__global__ __launch_bounds__(256) void gemm_bt(
    const _Float16* __restrict__ A, const _Float16* __restrict__ B,
    OT* __restrict__ C, int M, int N, int K) {
  __shared__ __align__(16) _Float16 As[128][32];
  __shared__ __align__(16) _Float16 Bs[128][32];
  int bm = blockIdx.x * 128, bn = blockIdx.y * 128;
  int t = threadIdx.x;
  int w = t >> 6, L = t & 63, lane15 = L & 15, quad = L >> 4;
  int wr = (w >> 1) * 64, wc = (w & 1) * 64;
  f32x4 acc[4][4] = {};
  for (int k0 = 0; k0 < K; k0 += 32) {
    __syncthreads();
    for (int r = 0; r < 2; r++) {
      int u = t + r * 256;           // 16-byte unit index, 512 total per tile
      int row = u >> 2, c8 = u & 3;  // LDS linear: row*64B + c8*16B
      gll16(&A[(size_t)(bm + row) * K + k0 + c8 * 8], &As[row][c8 * 8]);
      gll16(&B[(size_t)(bn + row) * K + k0 + c8 * 8], &Bs[row][c8 * 8]);
    }
    __syncthreads();
    f16x8 af[4], bf[4];
    for (int i = 0; i < 4; i++) af[i] = *(f16x8*)&As[wr + i * 16 + lane15][quad * 8];
    for (int j = 0; j < 4; j++) bf[j] = *(f16x8*)&Bs[wc + j * 16 + lane15][quad * 8];
    for (int i = 0; i < 4; i++)
      for (int j = 0; j < 4; j++)
        acc[i][j] = __builtin_amdgcn_mfma_f32_16x16x32_f16(af[i], bf[j], acc[i][j], 0, 0, 0);
  }
  for (int i = 0; i < 4; i++)
    for (int j = 0; j < 4; j++) {
      int gr = bm + wr + i * 16 + quad * 4;
      int gc = bn + wc + j * 16 + lane15;
      for (int r = 0; r < 4; r++) {
        float v = acc[i][j][r];
        if constexpr (std::is_same_v<OT, float>)
          C[(size_t)(gr + r) * N + gc] = v;
        else
          C[(size_t)(gr + r) * N + gc] = (_Float16)v;
      }
    }
}

// ---------------------------------------------------------------------------
// Scores (one pass): raw S -> P buffer, online per-row (m, l) -> m_g, rl_g.
// Grid (SEQ/64, NHEAD, BATCH), 512 threads = 8 waves: 4 row-groups x 2 col-halves.
// ---------------------------------------------------------------------------
__global__ __launch_bounds__(512) void scores_kernel(
    const _Float16* __restrict__ qkv, float* __restrict__ P,
    float* __restrict__ m_g, float* __restrict__ rl_g) {
  int ti = blockIdx.x, n = blockIdx.y, b = blockIdx.z;
  __shared__ __align__(16) _Float16 Qs[8][64][32];  // [kchunk][row][32]
  __shared__ __align__(16) _Float16 Ks[8][64][32];
  int t = threadIdx.x;
  int w = t >> 6, L = t & 63, lane15 = L & 15, quad = L >> 4;
  int r16 = (w & 3) * 16;   // row group
  int ch  = (w >> 2) * 32;  // col half
  // stage Q tile (32 KB) via global_load_lds: lane-linear 16B units
  for (int r = 0; r < 4; r++) {
    int u = t + r * 512;
    int kc = u >> 8, row = (u & 255) >> 2, c8 = u & 3;
    gll16(&qkv[((size_t)(b * SEQ + ti * 64 + row)) * QKVN + n * DHEAD + kc * 32 + c8 * 8],
          &Qs[kc][row][c8 * 8]);
  }
  float m[4], l[4];
  for (int r = 0; r < 4; r++) { m[r] = -INFINITY; l[r] = 0.f; }
  size_t Pbase = ((size_t)(b * NHEAD + n)) * SEQ * SEQ;
  int trow = ti * 64 + r16 + quad * 4;
  const float scale = 0.0625f;
  for (int si = 0; si <= ti; si++) {
    __syncthreads();  // Ks readers from previous iter done
    for (int r = 0; r < 4; r++) {
      int u = t + r * 512;
      int kc = u >> 8, row = (u & 255) >> 2, c8 = u & 3;
      gll16(&qkv[((size_t)(b * SEQ + si * 64 + row)) * QKVN + NHEAD * DHEAD + n * DHEAD + kc * 32 + c8 * 8],
            &Ks[kc][row][c8 * 8]);
    }
    __syncthreads();  // drains vmcnt (Q on first iter, K every iter)
    f32x4 s[2] = {};
    for (int kc = 0; kc < 8; kc++) {
      f16x8 aq = *(f16x8*)&Qs[kc][r16 + lane15][quad * 8];
      for (int j = 0; j < 2; j++) {
        f16x8 bk = *(f16x8*)&Ks[kc][ch + j * 16 + lane15][quad * 8];
        s[j] = __builtin_amdgcn_mfma_f32_16x16x32_f16(aq, bk, s[j], 0, 0, 0);
      }
    }
    for (int j = 0; j < 2; j++) {
      int col = si * 64 + ch + j * 16 + lane15;
      for (int r = 0; r < 4; r++) {
        float v = s[j][r] * scale;
        if (col > trow + r) v = -1e9f;
        s[j][r] = v;
        P[Pbase + (size_t)(trow + r) * SEQ + col] = v;  // raw S (masked = -1e9)
      }
    }
    for (int r = 0; r < 4; r++) {
      float mt = fmaxf(s[0][r], s[1][r]);
      for (int off = 1; off < 16; off <<= 1) mt = fmaxf(mt, __shfl_xor(mt, off, 64));
      float mn = fmaxf(m[r], mt);
      float sum = __expf(s[0][r] - mn) + __expf(s[1][r] - mn);
      for (int off = 1; off < 16; off <<= 1) sum += __shfl_xor(sum, off, 64);
      l[r] = l[r] * __expf(m[r] - mn) + sum;
      m[r] = mn;
    }
  }
  // combine the two col-halves' stats per row via LDS scratch (reuse Qs)
  __syncthreads();
  float* sM = (float*)&Qs[0][0][0];  // [2][64]
  float* sL = sM + 128;
  if (lane15 == 0) {
    for (int r = 0; r < 4; r++) {
      sM[(w >> 2) * 64 + r16 + quad * 4 + r] = m[r];
      sL[(w >> 2) * 64 + r16 + quad * 4 + r] = l[r];
    }
  }
  __syncthreads();
  if (t < 64) {
    float m0 = sM[t], m1 = sM[64 + t], l0 = sL[t], l1 = sL[64 + t];
    float mc = fmaxf(m0, m1);
    float lc = l0 * __expf(m0 - mc) + l1 * __expf(m1 - mc);
    size_t idx = ((size_t)(b * NHEAD + n)) * SEQ + ti * 64 + t;
    m_g[idx] = mc;
    rl_g[idx] = 1.0f / lc;
  }
}

// ---------------------------------------------------------------------------
// Normalize P in place (exp(s-m)*rl), accumulate head-mean -> Pmean (f16),
// zero-fill upper-triangle tiles. Grid (si, ti, b), 256 threads.
// ---------------------------------------------------------------------------
__global__ __launch_bounds__(256) void norm_mean_kernel(
    float* __restrict__ P, const float* __restrict__ m_g,
    const float* __restrict__ rl_g, _Float16* __restrict__ Pmean) {
  int si = blockIdx.x, ti = blockIdx.y, b = blockIdx.z;
  int t = threadIdx.x;
  int row = t >> 2, c16 = (t & 3) * 16;
  size_t tile_off = (size_t)(ti * 64 + row) * SEQ + si * 64 + c16;
  if (si > ti) {
    float4 z = make_float4(0.f, 0.f, 0.f, 0.f);
    for (int n = 0; n < 4; n++) {
      float* p = &P[((size_t)(b * NHEAD + n)) * SEQ * SEQ + tile_off];
      for (int q = 0; q < 4; q++) *(float4*)(p + q * 4) = z;
    }
    return;
  }
  float acc[16];
  for (int i = 0; i < 16; i++) acc[i] = 0.f;
  for (int n = 0; n < 4; n++) {
    size_t sidx = ((size_t)(b * NHEAD + n)) * SEQ + ti * 64 + row;
    float mm = m_g[sidx], rr = rl_g[sidx];
    float* p = &P[((size_t)(b * NHEAD + n)) * SEQ * SEQ + tile_off];
    for (int q = 0; q < 4; q++) {
      float4 v = *(float4*)(p + q * 4);
      float4 e;
      e.x = __expf(v.x - mm) * rr;
      e.y = __expf(v.y - mm) * rr;
      e.z = __expf(v.z - mm) * rr;
      e.w = __expf(v.w - mm) * rr;
      *(float4*)(p + q * 4) = e;
      acc[q * 4 + 0] += e.x; acc[q * 4 + 1] += e.y;
      acc[q * 4 + 2] += e.z; acc[q * 4 + 3] += e.w;
    }
  }
  _Float16 h[16];
  for (int i = 0; i < 16; i++) h[i] = (_Float16)(acc[i] * 0.25f);
  _Float16* pm = &Pmean[((size_t)(b * SEQ + ti * 64 + row)) * SEQ + si * 64 + c16];
  *(uint4*)pm = *(uint4*)h;
  *(uint4*)(pm + 8) = *(uint4*)(h + 8);
}

// ---------------------------------------------------------------------------
// m_attn[b][t][d] = sum_s Pmean[b][t][s] * v[b][s][d]  (f16 out, causal K-loop)
// ---------------------------------------------------------------------------
__global__ __launch_bounds__(256) void pv_kernel(
    const _Float16* __restrict__ Pmean, const _Float16* __restrict__ vT,
    _Float16* __restrict__ mattn) {
  int ti = blockIdx.x, b = blockIdx.y;
  __shared__ __align__(16) _Float16 Pm[2][64][32];
  __shared__ __align__(16) _Float16 Vs[2][256][32];
  int t = threadIdx.x;
  int w = t >> 6, L = t & 63, lane15 = L & 15, quad = L >> 4;
  f32x4 acc[16] = {};
  for (int si = 0; si <= ti; si++) {
    __syncthreads();
    for (int r = 0; r < 2; r++) {  // Pm: 8 KB = 512 units
      int u = t + r * 256;
      int kc = u >> 8, row = (u & 255) >> 2, c8 = u & 3;
      gll16(&Pmean[((size_t)(b * SEQ + ti * 64 + row)) * SEQ + si * 64 + kc * 32 + c8 * 8],
            &Pm[kc][row][c8 * 8]);
    }
    for (int r = 0; r < 8; r++) {  // Vs: 32 KB = 2048 units
      int u = t + r * 256;
      int kc = u >> 10, d = (u & 1023) >> 2, c8 = u & 3;
      gll16(&vT[((size_t)(b * DHEAD + d)) * SEQ + si * 64 + kc * 32 + c8 * 8],
            &Vs[kc][d][c8 * 8]);
    }
    __syncthreads();
    for (int kc = 0; kc < 2; kc++) {
      f16x8 ap = *(f16x8*)&Pm[kc][w * 16 + lane15][quad * 8];
      for (int j = 0; j < 16; j++) {
        f16x8 bv = *(f16x8*)&Vs[kc][j * 16 + lane15][quad * 8];
        acc[j] = __builtin_amdgcn_mfma_f32_16x16x32_f16(ap, bv, acc[j], 0, 0, 0);
      }
    }
  }
  for (int j = 0; j < 16; j++) {
    int row = b * SEQ + ti * 64 + w * 16 + quad * 4;
    int col = j * 16 + lane15;
    for (int r = 0; r < 4; r++)
      mattn[(size_t)(row + r) * DHEAD + col] = (_Float16)acc[j][r];
  }
}

// ---------------------------------------------------------------------------
// ws layout (f16 elems): wqkvT[2304*1024] | woutT[1024*256] | qkvb[16384*2304]
// | vT[16*256*1024] | stats fp32[2*16*4*1024]   (~90 MB)
// After scores, qkvb region is dead -> reused: mattn = qkvb, Pmean = qkvb+16384*256.
// xh (x as f16) lives in the P region of d_out until scores overwrites it.
// ---------------------------------------------------------------------------
extern "C" void kernel_launch(void* const* d_in, const int* in_sizes, int n_in,
                              void* d_out, int out_size, void* d_ws, size_t ws_size,
                              hipStream_t stream) {
  const float* x     = (const float*)d_in[0];
  const float* w_qkv = (const float*)d_in[1];
  const float* w_out = (const float*)d_in[2];
  float* out = (float*)d_out;
  float* P   = out + (size_t)BATCH * SEQ * HIDDEN;

  _Float16* wqkvT = (_Float16*)d_ws;
  _Float16* woutT = wqkvT + (size_t)QKVN * HIDDEN;
  _Float16* qkvb  = woutT + (size_t)HIDDEN * DHEAD;
  _Float16* vT    = qkvb + (size_t)BATCH * SEQ * QKVN;
  float*    m_g   = (float*)(vT + (size_t)BATCH * DHEAD * SEQ);
  float*    rl_g  = m_g + (size_t)BATCH * NHEAD * SEQ;
  _Float16* mattn = qkvb;                          // alias (qkvb dead after scores)
  _Float16* Pmean = qkvb + (size_t)BATCH * SEQ * DHEAD;
  _Float16* xh    = (_Float16*)P;                  // alias (overwritten by scores)

  f32_to_f16<<<BATCH * SEQ * HIDDEN / 1024, 256, 0, stream>>>(x, xh);
  transpose_to_f16<<<dim3(QKVN / 64, HIDDEN / 64), 256, 0, stream>>>(w_qkv, wqkvT, HIDDEN, QKVN);
  transpose_to_f16<<<dim3(HIDDEN / 64, DHEAD / 64), 256, 0, stream>>>(w_out, woutT, DHEAD, HIDDEN);
  gemm_bt<_Float16><<<dim3(BATCH * SEQ / 128, QKVN / 128), 256, 0, stream>>>(
      xh, wqkvT, qkvb, BATCH * SEQ, QKVN, HIDDEN);
  transpose_v<<<dim3(SEQ / 64, DHEAD / 64, BATCH), 256, 0, stream>>>(qkvb, vT);
  scores_kernel<<<dim3(SEQ / 64, NHEAD, BATCH), 512, 0, stream>>>(qkvb, P, m_g, rl_g);
  norm_mean_kernel<<<dim3(SEQ / 64, SEQ / 64, BATCH), 256, 0, stream>>>(P, m_g, rl_g, Pmean);
  pv_kernel<<<dim3(SEQ / 64, BATCH), 256, 0, stream>>>(Pmean, vT, mattn);
  gemm_bt<float><<<dim3(BATCH * SEQ / 128, HIDDEN / 128), 256, 0, stream>>>(
      mattn, woutT, out, BATCH * SEQ, HIDDEN, DHEAD);
}

// Round 3
// 728.868 us; speedup vs baseline: 1.1605x; 1.0475x over previous
//
#include <hip/hip_runtime.h>
#include <hip/hip_bf16.h>
#include <type_traits>

#define BATCH  16
#define SEQ    1024
#define HIDDEN 1024
#define NHEAD  4
#define DHEAD  256
#define QKVN   2304   // (2*NHEAD+1)*DHEAD

typedef _Float16 f16x8 __attribute__((ext_vector_type(8)));
typedef float    f32x4 __attribute__((ext_vector_type(4)));

__device__ __forceinline__ void gll16(const void* g, void* l) {
  __builtin_amdgcn_global_load_lds(
      (const __attribute__((address_space(1))) unsigned int*)g,
      (__attribute__((address_space(3))) unsigned int*)l, 16, 0, 0);
}

// ---------------------------------------------------------------------------
// fp32 -> f16 elementwise (x pre-conversion)
// ---------------------------------------------------------------------------
__global__ __launch_bounds__(256) void f32_to_f16(
    const float* __restrict__ in, _Float16* __restrict__ out) {
  int i4 = blockIdx.x * 256 + threadIdx.x;
  float4 v = ((const float4*)in)[i4];
  _Float16 h4[4] = {(_Float16)v.x, (_Float16)v.y, (_Float16)v.z, (_Float16)v.w};
  *(uint2*)&out[(size_t)i4 * 4] = *(uint2*)h4;
}

// ---------------------------------------------------------------------------
// Transpose fp32 [R][C] -> f16 [C][R]
// ---------------------------------------------------------------------------
__global__ __launch_bounds__(256) void transpose_to_f16(
    const float* __restrict__ in, _Float16* __restrict__ out, int R, int C) {
  __shared__ float tile[64][65];
  int bc = blockIdx.x * 64, br = blockIdx.y * 64;
  int t = threadIdx.x;
  int tr = t >> 6, tc = t & 63;
  for (int i = 0; i < 64; i += 4)
    tile[tr + i][tc] = in[(size_t)(br + tr + i) * C + bc + tc];
  __syncthreads();
  for (int i = 0; i < 64; i += 4)
    out[(size_t)(bc + tr + i) * R + br + tc] = (_Float16)tile[tc][tr + i];
}

// ---------------------------------------------------------------------------
// Transpose v slice of qkv (f16) into vT[b][d][s]
// ---------------------------------------------------------------------------
__global__ __launch_bounds__(256) void transpose_v(
    const _Float16* __restrict__ qkv, _Float16* __restrict__ vT) {
  __shared__ _Float16 tile[64][65];
  int b = blockIdx.z;
  int s0 = blockIdx.x * 64, d0 = blockIdx.y * 64;
  int t = threadIdx.x;
  int tr = t >> 6, tc = t & 63;
  for (int i = 0; i < 64; i += 4)
    tile[tr + i][tc] = qkv[((size_t)(b * SEQ + s0 + tr + i)) * QKVN + 2 * NHEAD * DHEAD + d0 + tc];
  __syncthreads();
  for (int i = 0; i < 64; i += 4)
    vT[((size_t)(b * DHEAD + d0 + tr + i)) * SEQ + s0 + tc] = tile[tc][tr + i];
}

// ---------------------------------------------------------------------------
// GEMM (B^T): C[m][n] = sum_k A[m][k]*B[n][k]; A,B f16; 128x128 tile BK=32.
// ---------------------------------------------------------------------------
template <typename OT>
__global__ __launch_bounds__(256) void gemm_bt(
    const _Float16* __restrict__ A, const _Float16* __restrict__ B,
    OT* __restrict__ C, int M, int N, int K) {
  __shared__ __align__(16) _Float16 As[128][32];
  __shared__ __align__(16) _Float16 Bs[128][32];
  int bm = blockIdx.x * 128, bn = blockIdx.y * 128;
  int t = threadIdx.x;
  int w = t >> 6, L = t & 63, lane15 = L & 15, quad = L >> 4;
  int wr = (w >> 1) * 64, wc = (w & 1) * 64;
  f32x4 acc[4][4] = {};
  for (int k0 = 0; k0 < K; k0 += 32) {
    __syncthreads();
    for (int r = 0; r < 2; r++) {
      int u = t + r * 256;
      int row = u >> 2, c8 = u & 3;
      gll16(&A[(size_t)(bm + row) * K + k0 + c8 * 8], &As[row][c8 * 8]);
      gll16(&B[(size_t)(bn + row) * K + k0 + c8 * 8], &Bs[row][c8 * 8]);
    }
    __syncthreads();
    f16x8 af[4], bf[4];
    for (int i = 0; i < 4; i++) af[i] = *(f16x8*)&As[wr + i * 16 + lane15][quad * 8];
    for (int j = 0; j < 4; j++) bf[j] = *(f16x8*)&Bs[wc + j * 16 + lane15][quad * 8];
    for (int i = 0; i < 4; i++)
      for (int j = 0; j < 4; j++)
        acc[i][j] = __builtin_amdgcn_mfma_f32_16x16x32_f16(af[i], bf[j], acc[i][j], 0, 0, 0);
  }
  for (int i = 0; i < 4; i++)
    for (int j = 0; j < 4; j++) {
      int gr = bm + wr + i * 16 + quad * 4;
      int gc = bn + wc + j * 16 + lane15;
      for (int r = 0; r < 4; r++) {
        float v = acc[i][j][r];
        if constexpr (std::is_same_v<OT, float>)
          C[(size_t)(gr + r) * N + gc] = v;
        else
          C[(size_t)(gr + r) * N + gc] = (_Float16)v;
      }
    }
}

// ---------------------------------------------------------------------------
// Scores + softmax, single MFMA pass: the 64-row strip's S tiles live in
// registers (s[16][2], 128 VGPR) across the online-softmax loop; after the
// stats merge, normalized P is written directly. Zero-fills the strip's
// upper-triangle. Grid (SEQ/64, NHEAD, BATCH), 512 thr = 4 row-grp x 2 col-half.
// ---------------------------------------------------------------------------
__global__ __launch_bounds__(512, 2) void scores_norm_kernel(
    const _Float16* __restrict__ qkv, float* __restrict__ P) {
  int ti = blockIdx.x, n = blockIdx.y, b = blockIdx.z;
  __shared__ __align__(16) _Float16 Qs[8][64][32];
  __shared__ __align__(16) _Float16 Ks[8][64][32];
  int t = threadIdx.x;
  int w = t >> 6, L = t & 63, lane15 = L & 15, quad = L >> 4;
  int r16 = (w & 3) * 16;   // row group
  int ch  = (w >> 2) * 32;  // col half
  // stage Q tile (32 KB)
  for (int r = 0; r < 4; r++) {
    int u = t + r * 512;
    int kc = u >> 8, row = (u & 255) >> 2, c8 = u & 3;
    gll16(&qkv[((size_t)(b * SEQ + ti * 64 + row)) * QKVN + n * DHEAD + kc * 32 + c8 * 8],
          &Qs[kc][row][c8 * 8]);
  }
  float m[4], l[4];
  for (int r = 0; r < 4; r++) { m[r] = -INFINITY; l[r] = 0.f; }
  f32x4 s[16][2];
  int trow = ti * 64 + r16 + quad * 4;
  const float scale = 0.0625f;
#pragma unroll
  for (int si = 0; si < 16; si++) {
    if (si <= ti) {
      __syncthreads();
      for (int r = 0; r < 4; r++) {
        int u = t + r * 512;
        int kc = u >> 8, row = (u & 255) >> 2, c8 = u & 3;
        gll16(&qkv[((size_t)(b * SEQ + si * 64 + row)) * QKVN + NHEAD * DHEAD + n * DHEAD + kc * 32 + c8 * 8],
              &Ks[kc][row][c8 * 8]);
      }
      __syncthreads();
      s[si][0] = (f32x4){0.f, 0.f, 0.f, 0.f};
      s[si][1] = (f32x4){0.f, 0.f, 0.f, 0.f};
      for (int kc = 0; kc < 8; kc++) {
        f16x8 aq = *(f16x8*)&Qs[kc][r16 + lane15][quad * 8];
        for (int j = 0; j < 2; j++) {
          f16x8 bk = *(f16x8*)&Ks[kc][ch + j * 16 + lane15][quad * 8];
          s[si][j] = __builtin_amdgcn_mfma_f32_16x16x32_f16(aq, bk, s[si][j], 0, 0, 0);
        }
      }
      for (int j = 0; j < 2; j++) {
        int col = si * 64 + ch + j * 16 + lane15;
        for (int r = 0; r < 4; r++) {
          float v = s[si][j][r] * scale;
          if (col > trow + r) v = -1e9f;
          s[si][j][r] = v;
        }
      }
      for (int r = 0; r < 4; r++) {
        float mt = fmaxf(s[si][0][r], s[si][1][r]);
        for (int off = 1; off < 16; off <<= 1) mt = fmaxf(mt, __shfl_xor(mt, off, 64));
        float mn = fmaxf(m[r], mt);
        float sum = __expf(s[si][0][r] - mn) + __expf(s[si][1][r] - mn);
        for (int off = 1; off < 16; off <<= 1) sum += __shfl_xor(sum, off, 64);
        l[r] = l[r] * __expf(m[r] - mn) + sum;
        m[r] = mn;
      }
    }
  }
  // merge the two col-halves' stats per row via LDS scratch (reuse Qs)
  __syncthreads();
  float* sM  = (float*)&Qs[0][0][0];  // [2][64]
  float* sL  = sM + 128;
  float* sMc = sM + 256;              // [64] merged max
  float* sRl = sM + 320;              // [64] merged 1/l
  if (lane15 == 0) {
    for (int r = 0; r < 4; r++) {
      sM[(w >> 2) * 64 + r16 + quad * 4 + r] = m[r];
      sL[(w >> 2) * 64 + r16 + quad * 4 + r] = l[r];
    }
  }
  __syncthreads();
  if (t < 64) {
    float m0 = sM[t], m1 = sM[64 + t], l0 = sL[t], l1 = sL[64 + t];
    float mc = fmaxf(m0, m1);
    float lc = l0 * __expf(m0 - mc) + l1 * __expf(m1 - mc);
    sMc[t] = mc;
    sRl[t] = 1.0f / lc;
  }
  __syncthreads();
  float mr[4], rl[4];
  for (int r = 0; r < 4; r++) {
    mr[r] = sMc[r16 + quad * 4 + r];
    rl[r] = sRl[r16 + quad * 4 + r];
  }
  size_t Pbase = ((size_t)(b * NHEAD + n)) * SEQ * SEQ;
  // write normalized P from registers
#pragma unroll
  for (int si = 0; si < 16; si++) {
    if (si <= ti) {
      for (int j = 0; j < 2; j++) {
        int col = si * 64 + ch + j * 16 + lane15;
        for (int r = 0; r < 4; r++) {
          float p = (col > trow + r) ? 0.f : __expf(s[si][j][r] - mr[r]) * rl[r];
          P[Pbase + (size_t)(trow + r) * SEQ + col] = p;
        }
      }
    }
  }
  // zero-fill the strip's fully-masked columns (col4 >= (ti+1)*16)
  {
    float4 z = make_float4(0.f, 0.f, 0.f, 0.f);
    int c4min = (ti + 1) * 16;
    for (int u = t; u < 16384; u += 512) {
      int row = u >> 8, c4 = u & 255;
      if (c4 >= c4min)
        *(float4*)&P[Pbase + (size_t)(ti * 64 + row) * SEQ + c4 * 4] = z;
    }
  }
}

// ---------------------------------------------------------------------------
// Pmean[b][t][s] = f16( mean_n P[b][n][t][s] ), causal tiles only.
// Grid (si, ti, b) with si>ti blocks exiting immediately.
// ---------------------------------------------------------------------------
__global__ __launch_bounds__(256) void pmean_kernel(
    const float* __restrict__ P, _Float16* __restrict__ Pmean) {
  int si = blockIdx.x, ti = blockIdx.y, b = blockIdx.z;
  if (si > ti) return;
  int t = threadIdx.x;
  int row = t >> 2, c16 = (t & 3) * 16;
  size_t tile_off = (size_t)(ti * 64 + row) * SEQ + si * 64 + c16;
  float acc[16];
  for (int i = 0; i < 16; i++) acc[i] = 0.f;
  for (int n = 0; n < 4; n++) {
    const float* p = &P[((size_t)(b * NHEAD + n)) * SEQ * SEQ + tile_off];
    for (int q = 0; q < 4; q++) {
      float4 v = *(const float4*)(p + q * 4);
      acc[q * 4 + 0] += v.x; acc[q * 4 + 1] += v.y;
      acc[q * 4 + 2] += v.z; acc[q * 4 + 3] += v.w;
    }
  }
  _Float16 h[16];
  for (int i = 0; i < 16; i++) h[i] = (_Float16)(acc[i] * 0.25f);
  _Float16* pm = &Pmean[((size_t)(b * SEQ + ti * 64 + row)) * SEQ + si * 64 + c16];
  *(uint4*)pm = *(uint4*)h;
  *(uint4*)(pm + 8) = *(uint4*)(h + 8);
}

// ---------------------------------------------------------------------------
// m_attn[b][t][d] = sum_s Pmean[b][t][s] * v[b][s][d]  (f16 out)
// ---------------------------------------------------------------------------
__global__ __launch_bounds__(256) void pv_kernel(
    const _Float16* __restrict__ Pmean, const _Float16* __restrict__ vT,
    _Float16* __restrict__ mattn) {
  int ti = blockIdx.x, b = blockIdx.y;
  __shared__ __align__(16) _Float16 Pm[2][64][32];
  __shared__ __align__(16) _Float16 Vs[2][256][32];
  int t = threadIdx.x;
  int w = t >> 6, L = t & 63, lane15 = L & 15, quad = L >> 4;
  f32x4 acc[16] = {};
  for (int si = 0; si <= ti; si++) {
    __syncthreads();
    for (int r = 0; r < 2; r++) {
      int u = t + r * 256;
      int kc = u >> 8, row = (u & 255) >> 2, c8 = u & 3;
      gll16(&Pmean[((size_t)(b * SEQ + ti * 64 + row)) * SEQ + si * 64 + kc * 32 + c8 * 8],
            &Pm[kc][row][c8 * 8]);
    }
    for (int r = 0; r < 8; r++) {
      int u = t + r * 256;
      int kc = u >> 10, d = (u & 1023) >> 2, c8 = u & 3;
      gll16(&vT[((size_t)(b * DHEAD + d)) * SEQ + si * 64 + kc * 32 + c8 * 8],
            &Vs[kc][d][c8 * 8]);
    }
    __syncthreads();
    for (int kc = 0; kc < 2; kc++) {
      f16x8 ap = *(f16x8*)&Pm[kc][w * 16 + lane15][quad * 8];
      for (int j = 0; j < 16; j++) {
        f16x8 bv = *(f16x8*)&Vs[kc][j * 16 + lane15][quad * 8];
        acc[j] = __builtin_amdgcn_mfma_f32_16x16x32_f16(ap, bv, acc[j], 0, 0, 0);
      }
    }
  }
  for (int j = 0; j < 16; j++) {
    int row = b * SEQ + ti * 64 + w * 16 + quad * 4;
    int col = j * 16 + lane15;
    for (int r = 0; r < 4; r++)
      mattn[(size_t)(row + r) * DHEAD + col] = (_Float16)acc[j][r];
  }
}

// ---------------------------------------------------------------------------
// ws layout (f16 elems): wqkvT[2304*1024] | woutT[1024*256] | qkvb[16384*2304]
// | vT[16*256*1024].  After scores, qkvb is dead -> mattn = qkvb,
// Pmean = qkvb + 16384*256.  xh (x as f16) lives in P region until scores.
// ---------------------------------------------------------------------------
extern "C" void kernel_launch(void* const* d_in, const int* in_sizes, int n_in,
                              void* d_out, int out_size, void* d_ws, size_t ws_size,
                              hipStream_t stream) {
  const float* x     = (const float*)d_in[0];
  const float* w_qkv = (const float*)d_in[1];
  const float* w_out = (const float*)d_in[2];
  float* out = (float*)d_out;
  float* P   = out + (size_t)BATCH * SEQ * HIDDEN;

  _Float16* wqkvT = (_Float16*)d_ws;
  _Float16* woutT = wqkvT + (size_t)QKVN * HIDDEN;
  _Float16* qkvb  = woutT + (size_t)HIDDEN * DHEAD;
  _Float16* vT    = qkvb + (size_t)BATCH * SEQ * QKVN;
  _Float16* mattn = qkvb;                              // alias (qkvb dead after scores)
  _Float16* Pmean = qkvb + (size_t)BATCH * SEQ * DHEAD;
  _Float16* xh    = (_Float16*)P;                      // alias (overwritten by scores)

  f32_to_f16<<<BATCH * SEQ * HIDDEN / 1024, 256, 0, stream>>>(x, xh);
  transpose_to_f16<<<dim3(QKVN / 64, HIDDEN / 64), 256, 0, stream>>>(w_qkv, wqkvT, HIDDEN, QKVN);
  transpose_to_f16<<<dim3(HIDDEN / 64, DHEAD / 64), 256, 0, stream>>>(w_out, woutT, DHEAD, HIDDEN);
  gemm_bt<_Float16><<<dim3(BATCH * SEQ / 128, QKVN / 128), 256, 0, stream>>>(
      xh, wqkvT, qkvb, BATCH * SEQ, QKVN, HIDDEN);
  transpose_v<<<dim3(SEQ / 64, DHEAD / 64, BATCH), 256, 0, stream>>>(qkvb, vT);
  scores_norm_kernel<<<dim3(SEQ / 64, NHEAD, BATCH), 512, 0, stream>>>(qkvb, P);
  pmean_kernel<<<dim3(SEQ / 64, SEQ / 64, BATCH), 256, 0, stream>>>(P, Pmean);
  pv_kernel<<<dim3(SEQ / 64, BATCH), 256, 0, stream>>>(Pmean, vT, mattn);
  gemm_bt<float><<<dim3(BATCH * SEQ / 128, HIDDEN / 128), 256, 0, stream>>>(
      mattn, woutT, out, BATCH * SEQ, HIDDEN, DHEAD);
}